// Round 5
// baseline (8391.142 us; speedup 1.0000x reference)
//
#include <hip/hip_runtime.h>
#include <hip/hip_bf16.h>

#define NC 4096
#define NSTEP 2500
#define NBLK 128  // 128 CUs x 32 rows each: halves broadcast+probe traffic
                  // and publisher count vs 256x16 (round-5 contention theory)

typedef float v4f __attribute__((ext_vector_type(4)));
typedef short v8s __attribute__((ext_vector_type(8)));
typedef unsigned int v4u __attribute__((ext_vector_type(4)));
typedef unsigned long long u64;

// ws layout (bytes):
//   [0,1024)        (unused -- was tags)
//   [1024,1088)     accum[16] (float)     -- readout partial sums
//   [4096,69632)    ring[2][4][4096] bf16 -- double-buffered r broadcast
//
// Self-validating transport: bit0 of every aligned ring u64 (4 bf16 values)
// is a step-parity stamp p(m) = (m>>1)&1 of the r_m it carries. 8B stores are
// single-copy atomic, so a reader granule is valid iff its u64 parities match
// the expected p(t). Drift is bounded <2 steps by the global dependency, so
// the only same-slot confusion candidate is r_t vs r_{t+-2}, which parity
// distinguishes. Ring layout is publisher-agnostic: moving from 256x16 to
// 128x32 rows changes nothing in the transport protocol.
//
// Discovery: single-outstanding 8B probe spin (round-2 protocol -- measured
// best; round-3 fetch-first and round-4 dual-probe both regressed via extra
// serialized RT and/or request-rate contention), then 64B fetch + verify.
#define WS_WORDS 17408  // zero first 69632 bytes (+ slot1 parity-invalid init)

__device__ __forceinline__ short f2bf_s(float f) {
  __hip_bfloat16 h = __float2bfloat16(f);
  return __bfloat16_as_short(h);
}

__device__ __forceinline__ unsigned pack_bf2(float a, float b) {
  unsigned ua = (unsigned short)f2bf_s(a);
  unsigned ub = (unsigned short)f2bf_s(b);
  return ua | (ub << 16);
}

__global__ void rnn_init(unsigned* ws_u) {
  int i = blockIdx.x * blockDim.x + threadIdx.x;
  if (i >= WS_WORDS) return;
  // slot0 (words [1024,9216)) = 0: r_0 = 0, parity bit0 = 0 = valid for t=0.
  // slot1 (words [9216,17408)): u64 = 0x...0001 -> parity 1 = "r_1 not here".
  unsigned v = 0u;
  if (i >= 9216 && (i & 1) == 0) v = 1u;
  ws_u[i] = v;
}

__global__ __launch_bounds__(512, 2) void rnn_persist(
    const float* __restrict__ x, const float* __restrict__ rec_w,
    const float* __restrict__ rec_b, const float* __restrict__ inp_w,
    const float* __restrict__ out_w, const float* __restrict__ mem_w,
    const float* __restrict__ noise, float* __restrict__ ws) {
  const int cu   = blockIdx.x;       // 0..127, owns rows [cu*32, cu*32+32)
  const int tid  = threadIdx.x;
  const int wave = tid >> 6;         // 0..7, K-slice [wave*512, +512)
  const int lane = tid & 63;
  const int n    = lane & 15;        // MFMA col (batch; valid < 4) / A row
  const int g    = lane >> 4;        // quad
  const int row0 = cu << 5;

  float* accum         = ws + 256;
  __hip_bfloat16* ring = (__hip_bfloat16*)(ws + 1024);

  // full r_t staged, swizzled: batch stride 1032 u64 = 8256 B (== 64 mod 128
  // -> B-frag ds_read_b128 worst case 2-way aliasing = free per m136)
  __shared__ u64 rbuf64[4 * 1032];       // 33 KB
  // red single-buffered (two barriers/step) to fit 2 row-tiles in LDS
  __shared__ v4f red0[8][64];            // 8 KB, row-tile 0 partials
  __shared__ v4f red1[8][64];            // 8 KB, row-tile 1 partials
  const unsigned short* rbufs = (const unsigned short*)rbuf64;

  // ---- W A-fragments: 2 row-tiles x 16. lane holds
  // W[row0 + tt*16 + n][k = wave*512 + f*32 + g*8 + j]
  v8s wfrag[32];
#pragma unroll
  for (int tt = 0; tt < 2; ++tt) {
    const float* wp =
        rec_w + (size_t)(row0 + tt * 16 + n) * NC + wave * 512 + g * 8;
#pragma unroll
    for (int f = 0; f < 16; ++f) {
      const float* p = wp + f * 32;
      float4 a = *(const float4*)p;
      float4 b = *(const float4*)(p + 4);
      v8s w;
      w[0] = f2bf_s(a.x); w[1] = f2bf_s(a.y); w[2] = f2bf_s(a.z); w[3] = f2bf_s(a.w);
      w[4] = f2bf_s(b.x); w[5] = f2bf_s(b.y); w[6] = f2bf_s(b.z); w[7] = f2bf_s(b.w);
      wfrag[tt * 16 + f] = w;
    }
  }

  // ---- tail waves (0: rows [row0,+16), 4: rows [row0+16,+16)) per-lane
  // state: rows row0 + roff + 4g + q, batch b = n&3
  const bool tail = (wave == 0) || (wave == 4);
  const int roff = (wave >> 2) << 4;  // 0 for wave0, 16 for wave4
  float rst[4] = {0, 0, 0, 0}, tmem[4] = {0, 0, 0, 0}, tout[4] = {0, 0, 0, 0};
  float bias[4] = {0, 0, 0, 0}, esmp[4] = {0, 0, 0, 0}, etst[4] = {0, 0, 0, 0};
  if (tail) {
    float4 bb = *(const float4*)(rec_b + row0 + roff + g * 4);
    bias[0] = bb.x; bias[1] = bb.y; bias[2] = bb.z; bias[3] = bb.w;
    const int b = n & 3;
    float xs0 = x[b * 4 + 0], xs1 = x[b * 4 + 1];
    float xt0 = x[b * 4 + 2], xt1 = x[b * 4 + 3];
#pragma unroll
    for (int q = 0; q < 4; ++q) {
      int i = row0 + roff + g * 4 + q;
      float w0 = inp_w[2 * i], w1 = inp_w[2 * i + 1];
      esmp[q] = xs0 * w0 + xs1 * w1;
      etst[q] = xt0 * w0 + xt1 * w1;
    }
  }

  for (int t = 0; t < NSTEP; ++t) {
    const int slot = t & 1;
    const unsigned par = (unsigned)((t >> 1) & 1);
    float4 nz = {0.f, 0.f, 0.f, 0.f};
    if (tail) {
      // prefetch noise; its latency hides under the poll/stage phase
      nz = *(const float4*)(noise + (size_t)t * NC + row0 + roff + g * 4);
    }

    // ---- merged poll+stage, per-wave autonomous: wave w consumes its own
    // K-slice granules; proceeds as soon as ITS slice of r_t arrives.
    {
      const v4u* src = (const v4u*)((const u64*)ring + (size_t)slot * 4096);
      const v4u* a0 = src + tid;
      const v4u* a1 = src + tid + 512;
      const v4u* a2 = src + tid + 1024;
      const v4u* a3 = src + tid + 1536;

      // single-outstanding 8B probe spin (round-2 protocol, measured best)
      int guard = 0;
      while (true) {
        u64 pr;
        asm volatile(
            "global_load_dwordx2 %0, %1, off sc1\n\t"
            "s_waitcnt vmcnt(0)"
            : "=v"(pr) : "v"((const u64*)a0) : "memory");
        if (__all((((unsigned)pr ^ par) & 1u) == 0u)) break;
        if (++guard > (1 << 19)) break;  // anti-hang valve
      }

      // full fetch + verify (sibling sectors may stagger; usually 1 pass)
      v4u d0, d1, d2, d3;
      guard = 0;
      while (true) {
        asm volatile(
            "global_load_dwordx4 %0, %4, off sc1\n\t"
            "global_load_dwordx4 %1, %5, off sc1\n\t"
            "global_load_dwordx4 %2, %6, off sc1\n\t"
            "global_load_dwordx4 %3, %7, off sc1\n\t"
            "s_waitcnt vmcnt(0)"
            : "=v"(d0), "=v"(d1), "=v"(d2), "=v"(d3)
            : "v"(a0), "v"(a1), "v"(a2), "v"(a3)
            : "memory");
        unsigned bad = (d0.x ^ par) | (d0.z ^ par) | (d1.x ^ par) |
                       (d1.z ^ par) | (d2.x ^ par) | (d2.z ^ par) |
                       (d3.x ^ par) | (d3.z ^ par);
        if (__all((bad & 1u) == 0u)) break;
        if (++guard > (1 << 19)) break;
      }

      // stage to wave-private LDS region (DS ops in-order within a wave;
      // this wave's MFMA reads exactly the region it writes)
      *(v4u*)(rbuf64 + 0 * 1032 + tid * 2) = d0;
      *(v4u*)(rbuf64 + 1 * 1032 + tid * 2) = d1;
      *(v4u*)(rbuf64 + 2 * 1032 + tid * 2) = d2;
      *(v4u*)(rbuf64 + 3 * 1032 + tid * 2) = d3;
    }

    // B2: previous step's red fully consumed by tail waves before overwrite.
    // Placed AFTER probe/fetch/stage so the fetch (long pole) overlaps the
    // producers' tail work from step t-1.
    __syncthreads();

    // ---- B-frags: lane holds r[b=n&3][k = wave*512+f*32+g*8+j], shared by
    // both row-tiles. 8 accumulator chains (2 tiles x 4).
    const unsigned short* rb = rbufs + (n & 3) * 4128 + wave * 512 + g * 8;
    v4f ac0 = {0.f, 0.f, 0.f, 0.f}, ac1 = {0.f, 0.f, 0.f, 0.f};
    v4f ac2 = {0.f, 0.f, 0.f, 0.f}, ac3 = {0.f, 0.f, 0.f, 0.f};
    v4f ad0 = {0.f, 0.f, 0.f, 0.f}, ad1 = {0.f, 0.f, 0.f, 0.f};
    v4f ad2 = {0.f, 0.f, 0.f, 0.f}, ad3 = {0.f, 0.f, 0.f, 0.f};
#pragma unroll
    for (int f = 0; f < 16; f += 4) {
      v8s b0 = *(const v8s*)(rb + (f + 0) * 32);
      v8s b1 = *(const v8s*)(rb + (f + 1) * 32);
      v8s b2 = *(const v8s*)(rb + (f + 2) * 32);
      v8s b3 = *(const v8s*)(rb + (f + 3) * 32);
      ac0 = __builtin_amdgcn_mfma_f32_16x16x32_bf16(wfrag[f + 0], b0, ac0, 0, 0, 0);
      ad0 = __builtin_amdgcn_mfma_f32_16x16x32_bf16(wfrag[16 + f + 0], b0, ad0, 0, 0, 0);
      ac1 = __builtin_amdgcn_mfma_f32_16x16x32_bf16(wfrag[f + 1], b1, ac1, 0, 0, 0);
      ad1 = __builtin_amdgcn_mfma_f32_16x16x32_bf16(wfrag[16 + f + 1], b1, ad1, 0, 0, 0);
      ac2 = __builtin_amdgcn_mfma_f32_16x16x32_bf16(wfrag[f + 2], b2, ac2, 0, 0, 0);
      ad2 = __builtin_amdgcn_mfma_f32_16x16x32_bf16(wfrag[16 + f + 2], b2, ad2, 0, 0, 0);
      ac3 = __builtin_amdgcn_mfma_f32_16x16x32_bf16(wfrag[f + 3], b3, ac3, 0, 0, 0);
      ad3 = __builtin_amdgcn_mfma_f32_16x16x32_bf16(wfrag[16 + f + 3], b3, ad3, 0, 0, 0);
    }
    red0[wave][lane] = (ac0 + ac1) + (ac2 + ac3);
    red1[wave][lane] = (ad0 + ad1) + (ad2 + ad3);
    __syncthreads();  // B1: reduction partials complete

    if (tail) {
      const v4f(*rr)[64] = (wave == 0) ? red0 : red1;
      // pairwise tree: 3-deep dependent chain
      v4f s01 = rr[0][lane] + rr[1][lane];
      v4f s23 = rr[2][lane] + rr[3][lane];
      v4f s45 = rr[4][lane] + rr[5][lane];
      v4f s67 = rr[6][lane] + rr[7][lane];
      v4f s = (s01 + s23) + (s45 + s67);
      const int ph = t / 500;  // 0 fix, 1 sample, 2 delay, 3 test, 4 response
#pragma unroll
      for (int q = 0; q < 4; ++q) {
        float e = (ph == 1) ? esmp[q] : ((ph == 3) ? etst[q] : 0.f);
        float pre = s[q] + bias[q] + e;
        float rl = pre > 0.f ? pre : 0.f;
        float nq = (q == 0) ? nz.x : (q == 1) ? nz.y : (q == 2) ? nz.z : nz.w;
        rst[q] = 0.8f * rst[q] + 0.2f * rl + 0.02f * nq;
      }
      if (t >= 1000 && t < 1500) {
#pragma unroll
        for (int q = 0; q < 4; ++q) tmem[q] += rst[q];
      }
      if (t >= 2000) {
#pragma unroll
        for (int q = 0; q < 4; ++q) tout[q] += rst[q];
      }
      if (n < 4) {  // publish r_{t+1}: parity-stamped, fire-and-forget
        u64 v = (u64)pack_bf2(rst[0], rst[1]) |
                ((u64)pack_bf2(rst[2], rst[3]) << 32);
        v = (v & ~1ull) | (u64)(((t + 1) >> 1) & 1u);
        u64* dst = (u64*)(ring + ((size_t)((t + 1) & 1) * 4 + n) * NC + row0 +
                          roff + g * 4);
        __hip_atomic_store(dst, v, __ATOMIC_RELAXED, __HIP_MEMORY_SCOPE_AGENT);
      }
      // no ack, no tag: validity travels inside the data
    }
  }

  // ---- readout partials: out[s][b][o] += sum_i w[o][i] * tsum[b][i]
  if (tail) {
    float pm0 = 0, pm1 = 0, po0 = 0, po1 = 0;
#pragma unroll
    for (int q = 0; q < 4; ++q) {
      int i = row0 + roff + g * 4 + q;
      pm0 += mem_w[i] * tmem[q];
      pm1 += mem_w[NC + i] * tmem[q];
      po0 += out_w[i] * tout[q];
      po1 += out_w[NC + i] * tout[q];
    }
    pm0 += __shfl_xor(pm0, 16); pm0 += __shfl_xor(pm0, 32);
    pm1 += __shfl_xor(pm1, 16); pm1 += __shfl_xor(pm1, 32);
    po0 += __shfl_xor(po0, 16); po0 += __shfl_xor(po0, 32);
    po1 += __shfl_xor(po1, 16); po1 += __shfl_xor(po1, 32);
    if (lane < 4) {
      atomicAdd(&accum[lane * 2 + 0], pm0);
      atomicAdd(&accum[lane * 2 + 1], pm1);
      atomicAdd(&accum[8 + lane * 2 + 0], po0);
      atomicAdd(&accum[8 + lane * 2 + 1], po1);
    }
  }
}

// Output is FLOAT32 (reference returns f32)
__global__ void rnn_final(const float* __restrict__ ws, float* __restrict__ out) {
  int i = threadIdx.x;
  if (i < 16) out[i] = ws[256 + i] * (1.0f / 500.0f);
}

extern "C" void kernel_launch(void* const* d_in, const int* in_sizes, int n_in,
                              void* d_out, int out_size, void* d_ws, size_t ws_size,
                              hipStream_t stream) {
  (void)in_sizes; (void)n_in; (void)out_size; (void)ws_size;
  const float* x     = (const float*)d_in[0];
  const float* rec_w = (const float*)d_in[1];
  const float* rec_b = (const float*)d_in[2];
  const float* inp_w = (const float*)d_in[3];
  const float* out_w = (const float*)d_in[4];
  const float* mem_w = (const float*)d_in[5];
  const float* noise = (const float*)d_in[6];
  float* ws = (float*)d_ws;

  rnn_init<<<(WS_WORDS + 255) / 256, 256, 0, stream>>>((unsigned*)d_ws);
  rnn_persist<<<NBLK, 512, 0, stream>>>(x, rec_w, rec_b, inp_w, out_w, mem_w,
                                        noise, ws);
  rnn_final<<<1, 64, 0, stream>>>(ws, (float*)d_out);
}

// Round 6
// 7480.299 us; speedup vs baseline: 1.1218x; 1.1218x over previous
//
#include <hip/hip_runtime.h>
#include <hip/hip_bf16.h>

#define NC 4096
#define NSTEP 2500

typedef float v4f __attribute__((ext_vector_type(4)));
typedef short v8s __attribute__((ext_vector_type(8)));
typedef unsigned int v4u __attribute__((ext_vector_type(4)));
typedef unsigned long long u64;

// ws layout (bytes):
//   [0,1024)        (unused -- was tags)
//   [1024,1088)     accum[16] (float)     -- readout partial sums
//   [4096,69632)    ring[2][4][4096] bf16 -- double-buffered r broadcast
//
// Self-validating transport: bit0 of every aligned ring u64 (4 bf16 values)
// is a step-parity stamp p(m) = (m>>1)&1 of the r_m it carries. 8B publishes
// are single-copy atomic, so a reader granule is valid iff its u64 parities
// match the expected p(t). Drift is bounded <2 steps by the global
// dependency, so the only same-slot confusion candidate is r_t vs r_{t+-2},
// which parity distinguishes.
//
// Publish (round 6): no-return global_atomic_swap_x2 instead of sc1 store.
// Round-5 evidence: WRITE_SIZE == exact publish volume -> sc1 stores write
// through to HBM and invalidate the MALL line, so every step's probe/fetch
// refills from HBM (~1000cy) instead of hitting MALL (~600cy). Atomics
// execute AT the MALL: line updated in place, stays resident.
//
// Discovery: single-outstanding 8B probe spin (round-2 protocol -- measured
// best; fetch-first r3 and dual-probe r4 both regressed), then 64B fetch
// + verify.
#define WS_WORDS 17408  // zero first 69632 bytes (+ slot1 parity-invalid init)

__device__ __forceinline__ short f2bf_s(float f) {
  __hip_bfloat16 h = __float2bfloat16(f);
  return __bfloat16_as_short(h);
}

__device__ __forceinline__ unsigned pack_bf2(float a, float b) {
  unsigned ua = (unsigned short)f2bf_s(a);
  unsigned ub = (unsigned short)f2bf_s(b);
  return ua | (ub << 16);
}

__global__ void rnn_init(unsigned* ws_u) {
  int i = blockIdx.x * blockDim.x + threadIdx.x;
  if (i >= WS_WORDS) return;
  // slot0 (words [1024,9216)) = 0: r_0 = 0, parity bit0 = 0 = valid for t=0.
  // slot1 (words [9216,17408)): u64 = 0x...0001 -> parity 1 = "r_1 not here".
  unsigned v = 0u;
  if (i >= 9216 && (i & 1) == 0) v = 1u;
  ws_u[i] = v;
}

__global__ __launch_bounds__(512, 2) void rnn_persist(
    const float* __restrict__ x, const float* __restrict__ rec_w,
    const float* __restrict__ rec_b, const float* __restrict__ inp_w,
    const float* __restrict__ out_w, const float* __restrict__ mem_w,
    const float* __restrict__ noise, float* __restrict__ ws) {
  const int cu   = blockIdx.x;       // 0..255, owns rows [cu*16, cu*16+16)
  const int tid  = threadIdx.x;
  const int wave = tid >> 6;         // 0..7, K-slice [wave*512, +512)
  const int lane = tid & 63;
  const int n    = lane & 15;        // MFMA col (batch; valid < 4) / A row
  const int g    = lane >> 4;        // quad
  const int row0 = cu << 4;

  float* accum         = ws + 256;
  __hip_bfloat16* ring = (__hip_bfloat16*)(ws + 1024);

  // full r_t staged, swizzled: batch stride 1032 u64 = 8256 B (== 64 mod 128
  // -> B-frag ds_read_b128 worst case 2-way aliasing = free per m136)
  __shared__ u64 rbuf64[4 * 1032];       // 33 KB
  __shared__ v4f red[2][8][64];          // 16 KB, double-buffered by t&1
  const unsigned short* rbufs = (const unsigned short*)rbuf64;

  // ---- W A-fragments in VGPRs: lane holds W[row0+n][k = wave*512+f*32+g*8+j]
  v8s wfrag[16];
  {
    const float* wp = rec_w + (size_t)(row0 + n) * NC + wave * 512 + g * 8;
#pragma unroll
    for (int f = 0; f < 16; ++f) {
      const float* p = wp + f * 32;
      float4 a = *(const float4*)p;
      float4 b = *(const float4*)(p + 4);
      v8s w;
      w[0] = f2bf_s(a.x); w[1] = f2bf_s(a.y); w[2] = f2bf_s(a.z); w[3] = f2bf_s(a.w);
      w[4] = f2bf_s(b.x); w[5] = f2bf_s(b.y); w[6] = f2bf_s(b.z); w[7] = f2bf_s(b.w);
      wfrag[f] = w;
    }
  }

  // ---- wave0 per-lane state: rows row0+4g+q, batch b=n&3
  float rst[4] = {0, 0, 0, 0}, tmem[4] = {0, 0, 0, 0}, tout[4] = {0, 0, 0, 0};
  float bias[4] = {0, 0, 0, 0}, esmp[4] = {0, 0, 0, 0}, etst[4] = {0, 0, 0, 0};
  if (wave == 0) {
    float4 bb = *(const float4*)(rec_b + row0 + g * 4);
    bias[0] = bb.x; bias[1] = bb.y; bias[2] = bb.z; bias[3] = bb.w;
    const int b = n & 3;
    float xs0 = x[b * 4 + 0], xs1 = x[b * 4 + 1];
    float xt0 = x[b * 4 + 2], xt1 = x[b * 4 + 3];
#pragma unroll
    for (int q = 0; q < 4; ++q) {
      int i = row0 + g * 4 + q;
      float w0 = inp_w[2 * i], w1 = inp_w[2 * i + 1];
      esmp[q] = xs0 * w0 + xs1 * w1;
      etst[q] = xt0 * w0 + xt1 * w1;
    }
  }

  for (int t = 0; t < NSTEP; ++t) {
    const int slot = t & 1;
    const unsigned par = (unsigned)((t >> 1) & 1);
    float4 nz = {0.f, 0.f, 0.f, 0.f};
    if (wave == 0) {
      // prefetch noise; its latency hides under the poll/stage phase
      nz = *(const float4*)(noise + (size_t)t * NC + row0 + g * 4);
    }

    // ---- merged poll+stage, per-wave autonomous: wave w consumes exactly
    // publishers [32w, 32w+32), covered by its own lanes' granules. No
    // pre-barrier; each wave proceeds as soon as ITS slice of r_t arrives.
    {
      const v4u* src = (const v4u*)((const u64*)ring + (size_t)slot * 4096);
      const v4u* a0 = src + tid;
      const v4u* a1 = src + tid + 512;
      const v4u* a2 = src + tid + 1024;
      const v4u* a3 = src + tid + 1536;

      // single-outstanding 8B probe spin (round-2 protocol, measured best)
      int guard = 0;
      while (true) {
        u64 pr;
        asm volatile(
            "global_load_dwordx2 %0, %1, off sc1\n\t"
            "s_waitcnt vmcnt(0)"
            : "=v"(pr) : "v"((const u64*)a0) : "memory");
        if (__all((((unsigned)pr ^ par) & 1u) == 0u)) break;
        if (++guard > (1 << 19)) break;  // anti-hang valve
      }

      // full fetch + verify (sibling sectors may stagger; usually 1 pass)
      v4u d0, d1, d2, d3;
      guard = 0;
      while (true) {
        asm volatile(
            "global_load_dwordx4 %0, %4, off sc1\n\t"
            "global_load_dwordx4 %1, %5, off sc1\n\t"
            "global_load_dwordx4 %2, %6, off sc1\n\t"
            "global_load_dwordx4 %3, %7, off sc1\n\t"
            "s_waitcnt vmcnt(0)"
            : "=v"(d0), "=v"(d1), "=v"(d2), "=v"(d3)
            : "v"(a0), "v"(a1), "v"(a2), "v"(a3)
            : "memory");
        unsigned bad = (d0.x ^ par) | (d0.z ^ par) | (d1.x ^ par) |
                       (d1.z ^ par) | (d2.x ^ par) | (d2.z ^ par) |
                       (d3.x ^ par) | (d3.z ^ par);
        if (__all((bad & 1u) == 0u)) break;
        if (++guard > (1 << 19)) break;
      }

      // stage to wave-private LDS region (DS ops in-order within a wave;
      // this wave's MFMA reads exactly the region it writes -> no barrier)
      *(v4u*)(rbuf64 + 0 * 1032 + tid * 2) = d0;
      *(v4u*)(rbuf64 + 1 * 1032 + tid * 2) = d1;
      *(v4u*)(rbuf64 + 2 * 1032 + tid * 2) = d2;
      *(v4u*)(rbuf64 + 3 * 1032 + tid * 2) = d3;
    }

    // ---- B-frags: lane holds r[b=n&3][k = wave*512+f*32+g*8+j]
    // 4 independent accumulator chains: dependent-latency -> issue-limited
    const unsigned short* rb = rbufs + (n & 3) * 4128 + wave * 512 + g * 8;
    v4f ac0 = {0.f, 0.f, 0.f, 0.f}, ac1 = {0.f, 0.f, 0.f, 0.f};
    v4f ac2 = {0.f, 0.f, 0.f, 0.f}, ac3 = {0.f, 0.f, 0.f, 0.f};
#pragma unroll
    for (int f = 0; f < 16; f += 4) {
      v8s b0 = *(const v8s*)(rb + (f + 0) * 32);
      v8s b1 = *(const v8s*)(rb + (f + 1) * 32);
      v8s b2 = *(const v8s*)(rb + (f + 2) * 32);
      v8s b3 = *(const v8s*)(rb + (f + 3) * 32);
      ac0 = __builtin_amdgcn_mfma_f32_16x16x32_bf16(wfrag[f + 0], b0, ac0, 0, 0, 0);
      ac1 = __builtin_amdgcn_mfma_f32_16x16x32_bf16(wfrag[f + 1], b1, ac1, 0, 0, 0);
      ac2 = __builtin_amdgcn_mfma_f32_16x16x32_bf16(wfrag[f + 2], b2, ac2, 0, 0, 0);
      ac3 = __builtin_amdgcn_mfma_f32_16x16x32_bf16(wfrag[f + 3], b3, ac3, 0, 0, 0);
    }
    red[slot][wave][lane] = (ac0 + ac1) + (ac2 + ac3);
    __syncthreads();  // reduction barrier (red double-buffered: only one/step)

    if (wave == 0) {
      // pairwise tree: 3-deep dependent chain instead of 7-deep
      v4f s01 = red[slot][0][lane] + red[slot][1][lane];
      v4f s23 = red[slot][2][lane] + red[slot][3][lane];
      v4f s45 = red[slot][4][lane] + red[slot][5][lane];
      v4f s67 = red[slot][6][lane] + red[slot][7][lane];
      v4f s = (s01 + s23) + (s45 + s67);
      const int ph = t / 500;  // 0 fix, 1 sample, 2 delay, 3 test, 4 response
#pragma unroll
      for (int q = 0; q < 4; ++q) {
        float e = (ph == 1) ? esmp[q] : ((ph == 3) ? etst[q] : 0.f);
        float pre = s[q] + bias[q] + e;
        float rl = pre > 0.f ? pre : 0.f;
        float nq = (q == 0) ? nz.x : (q == 1) ? nz.y : (q == 2) ? nz.z : nz.w;
        rst[q] = 0.8f * rst[q] + 0.2f * rl + 0.02f * nq;
      }
      if (t >= 1000 && t < 1500) {
#pragma unroll
        for (int q = 0; q < 4; ++q) tmem[q] += rst[q];
      }
      if (t >= 2000) {
#pragma unroll
        for (int q = 0; q < 4; ++q) tout[q] += rst[q];
      }
      if (n < 4) {  // publish r_{t+1}: parity-stamped atomic swap, no-return.
        // Executes AT the MALL: line updated in place + stays resident (no
        // HBM write-through / invalidate in the consumers' path).
        u64 v = (u64)pack_bf2(rst[0], rst[1]) |
                ((u64)pack_bf2(rst[2], rst[3]) << 32);
        v = (v & ~1ull) | (u64)(((t + 1) >> 1) & 1u);
        u64* dst =
            (u64*)(ring + ((size_t)((t + 1) & 1) * 4 + n) * NC + row0 + g * 4);
        asm volatile("global_atomic_swap_x2 %0, %1, off sc1"
                     :: "v"(dst), "v"(v) : "memory");
      }
      // no ack, no tag: validity travels inside the data
    }
  }

  // ---- readout partials: out[s][b][o] += sum_i w[o][i] * tsum[b][i]
  if (wave == 0) {
    float pm0 = 0, pm1 = 0, po0 = 0, po1 = 0;
#pragma unroll
    for (int q = 0; q < 4; ++q) {
      int i = row0 + g * 4 + q;
      pm0 += mem_w[i] * tmem[q];
      pm1 += mem_w[NC + i] * tmem[q];
      po0 += out_w[i] * tout[q];
      po1 += out_w[NC + i] * tout[q];
    }
    pm0 += __shfl_xor(pm0, 16); pm0 += __shfl_xor(pm0, 32);
    pm1 += __shfl_xor(pm1, 16); pm1 += __shfl_xor(pm1, 32);
    po0 += __shfl_xor(po0, 16); po0 += __shfl_xor(po0, 32);
    po1 += __shfl_xor(po1, 16); po1 += __shfl_xor(po1, 32);
    if (lane < 4) {
      atomicAdd(&accum[lane * 2 + 0], pm0);
      atomicAdd(&accum[lane * 2 + 1], pm1);
      atomicAdd(&accum[8 + lane * 2 + 0], po0);
      atomicAdd(&accum[8 + lane * 2 + 1], po1);
    }
  }
}

// Output is FLOAT32 (reference returns f32)
__global__ void rnn_final(const float* __restrict__ ws, float* __restrict__ out) {
  int i = threadIdx.x;
  if (i < 16) out[i] = ws[256 + i] * (1.0f / 500.0f);
}

extern "C" void kernel_launch(void* const* d_in, const int* in_sizes, int n_in,
                              void* d_out, int out_size, void* d_ws, size_t ws_size,
                              hipStream_t stream) {
  (void)in_sizes; (void)n_in; (void)out_size; (void)ws_size;
  const float* x     = (const float*)d_in[0];
  const float* rec_w = (const float*)d_in[1];
  const float* rec_b = (const float*)d_in[2];
  const float* inp_w = (const float*)d_in[3];
  const float* out_w = (const float*)d_in[4];
  const float* mem_w = (const float*)d_in[5];
  const float* noise = (const float*)d_in[6];
  float* ws = (float*)d_ws;

  rnn_init<<<(WS_WORDS + 255) / 256, 256, 0, stream>>>((unsigned*)d_ws);
  rnn_persist<<<256, 512, 0, stream>>>(x, rec_w, rec_b, inp_w, out_w, mem_w,
                                       noise, ws);
  rnn_final<<<1, 64, 0, stream>>>(ws, (float*)d_out);
}

// Round 7
// 7427.309 us; speedup vs baseline: 1.1298x; 1.0071x over previous
//
#include <hip/hip_runtime.h>
#include <hip/hip_bf16.h>

#define NC 4096
#define NSTEP 2500

typedef float v4f __attribute__((ext_vector_type(4)));
typedef short v8s __attribute__((ext_vector_type(8)));
typedef unsigned int v4u __attribute__((ext_vector_type(4)));
typedef unsigned long long u64;

// ws layout (bytes):
//   [0,1024)        (unused -- was tags)
//   [1024,1088)     accum[16] (float)     -- readout partial sums
//   [4096,69632)    ring[2][4][4096] bf16 -- double-buffered r broadcast
//
// Self-validating transport: bit0 of every aligned ring u64 (4 bf16 values)
// is a step-parity stamp p(m) = (m>>1)&1 of the r_m it carries. 8B publishes
// are single-copy atomic, so a reader granule is valid iff its u64 parities
// match the expected p(t). Drift is bounded <2 steps by the global
// dependency, so the only same-slot confusion candidate is r_t vs r_{t+-2},
// which parity distinguishes.
//
// Round-7 insight: vmcnt decrements IN ISSUE ORDER (m135). Wave0 issues the
// publish swap at the end of step t; its step-t+1 probe's vmcnt(0) therefore
// serially waits out the publish's full MALL round trip (~1000cy) EVERY
// step, and barrier B propagates that to the whole CU. Fix: wave0 (only)
// issues its full 64B fetch speculatively FIRST -- the fetch's vmcnt(0)
// retires the swap in parallel with the fetch RT, and since wave0 starts
// discovery ~400cy late (tail work), its publishers have often already
// landed (spec hit = 1 RT total). On miss: standard probe spin + refetch.
// Waves 1..7 keep the round-2 probe-first protocol (spec-fetch for ALL
// waves was round 3's 25% regression; this is 1/8 that traffic).
#define WS_WORDS 17408  // zero first 69632 bytes (+ slot1 parity-invalid init)

__device__ __forceinline__ short f2bf_s(float f) {
  __hip_bfloat16 h = __float2bfloat16(f);
  return __bfloat16_as_short(h);
}

__device__ __forceinline__ unsigned pack_bf2(float a, float b) {
  unsigned ua = (unsigned short)f2bf_s(a);
  unsigned ub = (unsigned short)f2bf_s(b);
  return ua | (ub << 16);
}

__global__ void rnn_init(unsigned* ws_u) {
  int i = blockIdx.x * blockDim.x + threadIdx.x;
  if (i >= WS_WORDS) return;
  // slot0 (words [1024,9216)) = 0: r_0 = 0, parity bit0 = 0 = valid for t=0.
  // slot1 (words [9216,17408)): u64 = 0x...0001 -> parity 1 = "r_1 not here".
  unsigned v = 0u;
  if (i >= 9216 && (i & 1) == 0) v = 1u;
  ws_u[i] = v;
}

__global__ __launch_bounds__(512, 2) void rnn_persist(
    const float* __restrict__ x, const float* __restrict__ rec_w,
    const float* __restrict__ rec_b, const float* __restrict__ inp_w,
    const float* __restrict__ out_w, const float* __restrict__ mem_w,
    const float* __restrict__ noise, float* __restrict__ ws) {
  const int cu   = blockIdx.x;       // 0..255, owns rows [cu*16, cu*16+16)
  const int tid  = threadIdx.x;
  const int wave = tid >> 6;         // 0..7, K-slice [wave*512, +512)
  const int lane = tid & 63;
  const int n    = lane & 15;        // MFMA col (batch; valid < 4) / A row
  const int g    = lane >> 4;        // quad
  const int row0 = cu << 4;

  float* accum         = ws + 256;
  __hip_bfloat16* ring = (__hip_bfloat16*)(ws + 1024);

  // full r_t staged, swizzled: batch stride 1032 u64 = 8256 B (== 64 mod 128
  // -> B-frag ds_read_b128 worst case 2-way aliasing = free per m136)
  __shared__ u64 rbuf64[4 * 1032];       // 33 KB
  __shared__ v4f red[2][8][64];          // 16 KB, double-buffered by t&1
  const unsigned short* rbufs = (const unsigned short*)rbuf64;

  // ---- W A-fragments in VGPRs: lane holds W[row0+n][k = wave*512+f*32+g*8+j]
  v8s wfrag[16];
  {
    const float* wp = rec_w + (size_t)(row0 + n) * NC + wave * 512 + g * 8;
#pragma unroll
    for (int f = 0; f < 16; ++f) {
      const float* p = wp + f * 32;
      float4 a = *(const float4*)p;
      float4 b = *(const float4*)(p + 4);
      v8s w;
      w[0] = f2bf_s(a.x); w[1] = f2bf_s(a.y); w[2] = f2bf_s(a.z); w[3] = f2bf_s(a.w);
      w[4] = f2bf_s(b.x); w[5] = f2bf_s(b.y); w[6] = f2bf_s(b.z); w[7] = f2bf_s(b.w);
      wfrag[f] = w;
    }
  }

  // ---- wave0 per-lane state: rows row0+4g+q, batch b=n&3
  float rst[4] = {0, 0, 0, 0}, tmem[4] = {0, 0, 0, 0}, tout[4] = {0, 0, 0, 0};
  float bias[4] = {0, 0, 0, 0}, esmp[4] = {0, 0, 0, 0}, etst[4] = {0, 0, 0, 0};
  if (wave == 0) {
    float4 bb = *(const float4*)(rec_b + row0 + g * 4);
    bias[0] = bb.x; bias[1] = bb.y; bias[2] = bb.z; bias[3] = bb.w;
    const int b = n & 3;
    float xs0 = x[b * 4 + 0], xs1 = x[b * 4 + 1];
    float xt0 = x[b * 4 + 2], xt1 = x[b * 4 + 3];
#pragma unroll
    for (int q = 0; q < 4; ++q) {
      int i = row0 + g * 4 + q;
      float w0 = inp_w[2 * i], w1 = inp_w[2 * i + 1];
      esmp[q] = xs0 * w0 + xs1 * w1;
      etst[q] = xt0 * w0 + xt1 * w1;
    }
  }

  for (int t = 0; t < NSTEP; ++t) {
    const int slot = t & 1;
    const unsigned par = (unsigned)((t >> 1) & 1);
    float4 nz = {0.f, 0.f, 0.f, 0.f};
    if (wave == 0) {
      // prefetch noise; its latency hides under the fetch/poll phase
      nz = *(const float4*)(noise + (size_t)t * NC + row0 + g * 4);
    }

    // ---- merged poll+stage, per-wave autonomous: wave w consumes exactly
    // publishers [32w, 32w+32), covered by its own lanes' granules. No
    // pre-barrier; each wave proceeds as soon as ITS slice of r_t arrives.
    {
      const v4u* src = (const v4u*)((const u64*)ring + (size_t)slot * 4096);
      const v4u* a0 = src + tid;
      const v4u* a1 = src + tid + 512;
      const v4u* a2 = src + tid + 1024;
      const v4u* a3 = src + tid + 1536;
      v4u d0, d1, d2, d3;
      bool need = true;

      if (wave == 0) {
        // speculative full fetch: its vmcnt(0) retires the outstanding
        // publish swap IN PARALLEL with the fetch RT (vmcnt is in-order,
        // so any wait here was going to drain the swap anyway), and wave0
        // starts late enough that publishers 0..31 often already landed.
        asm volatile(
            "global_load_dwordx4 %0, %4, off sc1\n\t"
            "global_load_dwordx4 %1, %5, off sc1\n\t"
            "global_load_dwordx4 %2, %6, off sc1\n\t"
            "global_load_dwordx4 %3, %7, off sc1\n\t"
            "s_waitcnt vmcnt(0)"
            : "=v"(d0), "=v"(d1), "=v"(d2), "=v"(d3)
            : "v"(a0), "v"(a1), "v"(a2), "v"(a3)
            : "memory");
        unsigned bad = (d0.x ^ par) | (d0.z ^ par) | (d1.x ^ par) |
                       (d1.z ^ par) | (d2.x ^ par) | (d2.z ^ par) |
                       (d3.x ^ par) | (d3.z ^ par);
        need = !__all((bad & 1u) == 0u);
      }

      if (need) {
        // single-outstanding 8B probe spin (round-2 protocol, measured best)
        int guard = 0;
        while (true) {
          u64 pr;
          asm volatile(
              "global_load_dwordx2 %0, %1, off sc1\n\t"
              "s_waitcnt vmcnt(0)"
              : "=v"(pr) : "v"((const u64*)a0) : "memory");
          if (__all((((unsigned)pr ^ par) & 1u) == 0u)) break;
          if (++guard > (1 << 19)) break;  // anti-hang valve
        }

        // full fetch + verify (sibling sectors may stagger; usually 1 pass)
        guard = 0;
        while (true) {
          asm volatile(
              "global_load_dwordx4 %0, %4, off sc1\n\t"
              "global_load_dwordx4 %1, %5, off sc1\n\t"
              "global_load_dwordx4 %2, %6, off sc1\n\t"
              "global_load_dwordx4 %3, %7, off sc1\n\t"
              "s_waitcnt vmcnt(0)"
              : "=v"(d0), "=v"(d1), "=v"(d2), "=v"(d3)
              : "v"(a0), "v"(a1), "v"(a2), "v"(a3)
              : "memory");
          unsigned bad = (d0.x ^ par) | (d0.z ^ par) | (d1.x ^ par) |
                         (d1.z ^ par) | (d2.x ^ par) | (d2.z ^ par) |
                         (d3.x ^ par) | (d3.z ^ par);
          if (__all((bad & 1u) == 0u)) break;
          if (++guard > (1 << 19)) break;
        }
      }

      // stage to wave-private LDS region (DS ops in-order within a wave;
      // this wave's MFMA reads exactly the region it writes -> no barrier)
      *(v4u*)(rbuf64 + 0 * 1032 + tid * 2) = d0;
      *(v4u*)(rbuf64 + 1 * 1032 + tid * 2) = d1;
      *(v4u*)(rbuf64 + 2 * 1032 + tid * 2) = d2;
      *(v4u*)(rbuf64 + 3 * 1032 + tid * 2) = d3;
    }

    // ---- B-frags: lane holds r[b=n&3][k = wave*512+f*32+g*8+j]
    // 4 independent accumulator chains: dependent-latency -> issue-limited
    const unsigned short* rb = rbufs + (n & 3) * 4128 + wave * 512 + g * 8;
    v4f ac0 = {0.f, 0.f, 0.f, 0.f}, ac1 = {0.f, 0.f, 0.f, 0.f};
    v4f ac2 = {0.f, 0.f, 0.f, 0.f}, ac3 = {0.f, 0.f, 0.f, 0.f};
#pragma unroll
    for (int f = 0; f < 16; f += 4) {
      v8s b0 = *(const v8s*)(rb + (f + 0) * 32);
      v8s b1 = *(const v8s*)(rb + (f + 1) * 32);
      v8s b2 = *(const v8s*)(rb + (f + 2) * 32);
      v8s b3 = *(const v8s*)(rb + (f + 3) * 32);
      ac0 = __builtin_amdgcn_mfma_f32_16x16x32_bf16(wfrag[f + 0], b0, ac0, 0, 0, 0);
      ac1 = __builtin_amdgcn_mfma_f32_16x16x32_bf16(wfrag[f + 1], b1, ac1, 0, 0, 0);
      ac2 = __builtin_amdgcn_mfma_f32_16x16x32_bf16(wfrag[f + 2], b2, ac2, 0, 0, 0);
      ac3 = __builtin_amdgcn_mfma_f32_16x16x32_bf16(wfrag[f + 3], b3, ac3, 0, 0, 0);
    }
    red[slot][wave][lane] = (ac0 + ac1) + (ac2 + ac3);
    __syncthreads();  // reduction barrier (red double-buffered: only one/step)

    if (wave == 0) {
      // pairwise tree: 3-deep dependent chain instead of 7-deep
      v4f s01 = red[slot][0][lane] + red[slot][1][lane];
      v4f s23 = red[slot][2][lane] + red[slot][3][lane];
      v4f s45 = red[slot][4][lane] + red[slot][5][lane];
      v4f s67 = red[slot][6][lane] + red[slot][7][lane];
      v4f s = (s01 + s23) + (s45 + s67);
      const int ph = t / 500;  // 0 fix, 1 sample, 2 delay, 3 test, 4 response
#pragma unroll
      for (int q = 0; q < 4; ++q) {
        float e = (ph == 1) ? esmp[q] : ((ph == 3) ? etst[q] : 0.f);
        float pre = s[q] + bias[q] + e;
        float rl = pre > 0.f ? pre : 0.f;
        float nq = (q == 0) ? nz.x : (q == 1) ? nz.y : (q == 2) ? nz.z : nz.w;
        rst[q] = 0.8f * rst[q] + 0.2f * rl + 0.02f * nq;
      }
      if (n < 4) {  // publish FIRST (before bookkeeping): every cycle earlier
                    // here is a cycle off every consumer's discovery chain.
        u64 v = (u64)pack_bf2(rst[0], rst[1]) |
                ((u64)pack_bf2(rst[2], rst[3]) << 32);
        v = (v & ~1ull) | (u64)(((t + 1) >> 1) & 1u);
        u64* dst =
            (u64*)(ring + ((size_t)((t + 1) & 1) * 4 + n) * NC + row0 + g * 4);
        asm volatile("global_atomic_swap_x2 %0, %1, off sc1"
                     :: "v"(dst), "v"(v) : "memory");
      }
      if (t >= 1000 && t < 1500) {
#pragma unroll
        for (int q = 0; q < 4; ++q) tmem[q] += rst[q];
      }
      if (t >= 2000) {
#pragma unroll
        for (int q = 0; q < 4; ++q) tout[q] += rst[q];
      }
      // no ack, no tag: validity travels inside the data
    }
  }

  // ---- readout partials: out[s][b][o] += sum_i w[o][i] * tsum[b][i]
  if (wave == 0) {
    float pm0 = 0, pm1 = 0, po0 = 0, po1 = 0;
#pragma unroll
    for (int q = 0; q < 4; ++q) {
      int i = row0 + g * 4 + q;
      pm0 += mem_w[i] * tmem[q];
      pm1 += mem_w[NC + i] * tmem[q];
      po0 += out_w[i] * tout[q];
      po1 += out_w[NC + i] * tout[q];
    }
    pm0 += __shfl_xor(pm0, 16); pm0 += __shfl_xor(pm0, 32);
    pm1 += __shfl_xor(pm1, 16); pm1 += __shfl_xor(pm1, 32);
    po0 += __shfl_xor(po0, 16); po0 += __shfl_xor(po0, 32);
    po1 += __shfl_xor(po1, 16); po1 += __shfl_xor(po1, 32);
    if (lane < 4) {
      atomicAdd(&accum[lane * 2 + 0], pm0);
      atomicAdd(&accum[lane * 2 + 1], pm1);
      atomicAdd(&accum[8 + lane * 2 + 0], po0);
      atomicAdd(&accum[8 + lane * 2 + 1], po1);
    }
  }
}

// Output is FLOAT32 (reference returns f32)
__global__ void rnn_final(const float* __restrict__ ws, float* __restrict__ out) {
  int i = threadIdx.x;
  if (i < 16) out[i] = ws[256 + i] * (1.0f / 500.0f);
}

extern "C" void kernel_launch(void* const* d_in, const int* in_sizes, int n_in,
                              void* d_out, int out_size, void* d_ws, size_t ws_size,
                              hipStream_t stream) {
  (void)in_sizes; (void)n_in; (void)out_size; (void)ws_size;
  const float* x     = (const float*)d_in[0];
  const float* rec_w = (const float*)d_in[1];
  const float* rec_b = (const float*)d_in[2];
  const float* inp_w = (const float*)d_in[3];
  const float* out_w = (const float*)d_in[4];
  const float* mem_w = (const float*)d_in[5];
  const float* noise = (const float*)d_in[6];
  float* ws = (float*)d_ws;

  rnn_init<<<(WS_WORDS + 255) / 256, 256, 0, stream>>>((unsigned*)d_ws);
  rnn_persist<<<256, 512, 0, stream>>>(x, rec_w, rec_b, inp_w, out_w, mem_w,
                                       noise, ws);
  rnn_final<<<1, 64, 0, stream>>>(ws, (float*)d_out);
}

// Round 9
// 7329.649 us; speedup vs baseline: 1.1448x; 1.0133x over previous
//
#include <hip/hip_runtime.h>
#include <hip/hip_bf16.h>

#define NC 4096
#define NSTEP 2500

typedef float v4f __attribute__((ext_vector_type(4)));
typedef short v8s __attribute__((ext_vector_type(8)));
typedef unsigned int v4u __attribute__((ext_vector_type(4)));
typedef unsigned long long u64;

// ws layout (bytes):
//   [0,1024)        (unused -- was tags)
//   [1024,1088)     accum[16] (float)     -- readout partial sums
//   [4096,69632)    ring[2][4][4096] bf16 -- double-buffered r broadcast
//
// Self-validating transport: bit0 of every aligned ring u64 (4 bf16 values)
// is a step-parity stamp p(m) = (m>>1)&1 of the r_m it carries. 8B publishes
// are single-copy atomic, so a reader granule is valid iff its u64 parities
// match the expected p(t). Drift is bounded <2 steps by the global
// dependency, so the only same-slot confusion candidate is r_t vs r_{t+-2},
// which parity distinguishes.
//
// Round-9 = round-8 resubmission (r8 failure matched r1's infra signature;
// protocol re-audited sound) + collapsing anti-hang valve: after a first
// valve fire, the spin budget drops to 256 iters so a genuine protocol
// failure finishes in <1s as passed:false instead of an opaque container
// timeout.
//  (a) raw barrier (s_waitcnt lgkmcnt(0); s_barrier) -- __syncthreads()
//      emits a full vmcnt(0) drain before s_barrier, which forcibly retires
//      anything we try to keep in flight across the barrier. Cross-wave data
//      here moves ONLY through LDS (red, rbuf), so lgkmcnt(0) suffices.
//  (b) noise software-pipelined: wave0 issues noise row t+1 during body(t)
//      (after discovery, before MFMA), double-buffered in VGPRs. Noise lines
//      are first-touch (HBM ~900cy); previously the discovery vmcnt(0)
//      waited them out on the gating path every step.
//  (c) masked progressive probe: lanes whose granule parity already matched
//      stop re-loading -- probe line traffic decays during the wait window
//      (r4 measured the traffic sensitivity of this interconnect).
#define WS_WORDS 17408  // zero first 69632 bytes (+ slot1 parity-invalid init)

__device__ __forceinline__ short f2bf_s(float f) {
  __hip_bfloat16 h = __float2bfloat16(f);
  return __bfloat16_as_short(h);
}

__device__ __forceinline__ unsigned pack_bf2(float a, float b) {
  unsigned ua = (unsigned short)f2bf_s(a);
  unsigned ub = (unsigned short)f2bf_s(b);
  return ua | (ub << 16);
}

// barrier WITHOUT the compiler's vmcnt(0) drain: LDS ordering only.
__device__ __forceinline__ void barrier_lds_only() {
  asm volatile("s_waitcnt lgkmcnt(0)\n\ts_barrier" ::: "memory");
}

__global__ void rnn_init(unsigned* ws_u) {
  int i = blockIdx.x * blockDim.x + threadIdx.x;
  if (i >= WS_WORDS) return;
  // slot0 (words [1024,9216)) = 0: r_0 = 0, parity bit0 = 0 = valid for t=0.
  // slot1 (words [9216,17408)): u64 = 0x...0001 -> parity 1 = "r_1 not here".
  unsigned v = 0u;
  if (i >= 9216 && (i & 1) == 0) v = 1u;
  ws_u[i] = v;
}

__global__ __launch_bounds__(512, 2) void rnn_persist(
    const float* __restrict__ x, const float* __restrict__ rec_w,
    const float* __restrict__ rec_b, const float* __restrict__ inp_w,
    const float* __restrict__ out_w, const float* __restrict__ mem_w,
    const float* __restrict__ noise, float* __restrict__ ws) {
  const int cu   = blockIdx.x;       // 0..255, owns rows [cu*16, cu*16+16)
  const int tid  = threadIdx.x;
  const int wave = tid >> 6;         // 0..7, K-slice [wave*512, +512)
  const int lane = tid & 63;
  const int n    = lane & 15;        // MFMA col (batch; valid < 4) / A row
  const int g    = lane >> 4;        // quad
  const int row0 = cu << 4;

  float* accum         = ws + 256;
  __hip_bfloat16* ring = (__hip_bfloat16*)(ws + 1024);

  // full r_t staged, swizzled: batch stride 1032 u64 = 8256 B (== 64 mod 128
  // -> B-frag ds_read_b128 worst case 2-way aliasing = free per m136)
  __shared__ u64 rbuf64[4 * 1032];       // 33 KB
  __shared__ v4f red[2][8][64];          // 16 KB, double-buffered by t&1
  const unsigned short* rbufs = (const unsigned short*)rbuf64;

  // collapsing anti-hang valve: normal budget never fires; after a first
  // fire (protocol dead), budget drops so the kernel exits fast and the
  // harness reports passed:false instead of a container timeout.
  int vlimit = 1 << 19;

  // ---- W A-fragments in VGPRs: lane holds W[row0+n][k = wave*512+f*32+g*8+j]
  v8s wfrag[16];
  {
    const float* wp = rec_w + (size_t)(row0 + n) * NC + wave * 512 + g * 8;
#pragma unroll
    for (int f = 0; f < 16; ++f) {
      const float* p = wp + f * 32;
      float4 a = *(const float4*)p;
      float4 b = *(const float4*)(p + 4);
      v8s w;
      w[0] = f2bf_s(a.x); w[1] = f2bf_s(a.y); w[2] = f2bf_s(a.z); w[3] = f2bf_s(a.w);
      w[4] = f2bf_s(b.x); w[5] = f2bf_s(b.y); w[6] = f2bf_s(b.z); w[7] = f2bf_s(b.w);
      wfrag[f] = w;
    }
  }

  // ---- wave0 per-lane state: rows row0+4g+q, batch b=n&3
  float rst[4] = {0, 0, 0, 0}, tmem[4] = {0, 0, 0, 0}, tout[4] = {0, 0, 0, 0};
  float bias[4] = {0, 0, 0, 0}, esmp[4] = {0, 0, 0, 0}, etst[4] = {0, 0, 0, 0};
  float4 nz_cur = {0.f, 0.f, 0.f, 0.f};
  if (wave == 0) {
    float4 bb = *(const float4*)(rec_b + row0 + g * 4);
    bias[0] = bb.x; bias[1] = bb.y; bias[2] = bb.z; bias[3] = bb.w;
    const int b = n & 3;
    float xs0 = x[b * 4 + 0], xs1 = x[b * 4 + 1];
    float xt0 = x[b * 4 + 2], xt1 = x[b * 4 + 3];
#pragma unroll
    for (int q = 0; q < 4; ++q) {
      int i = row0 + g * 4 + q;
      float w0 = inp_w[2 * i], w1 = inp_w[2 * i + 1];
      esmp[q] = xs0 * w0 + xs1 * w1;
      etst[q] = xt0 * w0 + xt1 * w1;
    }
    nz_cur = *(const float4*)(noise + row0 + g * 4);  // row 0 prologue
  }

  for (int t = 0; t < NSTEP; ++t) {
    const int slot = t & 1;
    const unsigned par = (unsigned)((t >> 1) & 1);

    // ---- merged poll+stage, per-wave autonomous: wave w consumes exactly
    // publishers [32w, 32w+32), covered by its own lanes' granules. No
    // pre-barrier; each wave proceeds as soon as ITS slice of r_t arrives.
    {
      const v4u* src = (const v4u*)((const u64*)ring + (size_t)slot * 4096);
      const v4u* a0 = src + tid;
      const v4u* a1 = src + tid + 512;
      const v4u* a2 = src + tid + 1024;
      const v4u* a3 = src + tid + 1536;
      v4u d0, d1, d2, d3;
      bool need = true;

      if (wave == 0) {
        // speculative full fetch: its vmcnt(0) retires the outstanding
        // publish swap + last round's noise prefetch IN PARALLEL with the
        // fetch RT, and wave0 starts late enough (tail work) that its
        // publishers 0..31 often already landed.
        asm volatile(
            "global_load_dwordx4 %0, %4, off sc1\n\t"
            "global_load_dwordx4 %1, %5, off sc1\n\t"
            "global_load_dwordx4 %2, %6, off sc1\n\t"
            "global_load_dwordx4 %3, %7, off sc1\n\t"
            "s_waitcnt vmcnt(0)"
            : "=v"(d0), "=v"(d1), "=v"(d2), "=v"(d3)
            : "v"(a0), "v"(a1), "v"(a2), "v"(a3)
            : "memory");
        unsigned bad = (d0.x ^ par) | (d0.z ^ par) | (d1.x ^ par) |
                       (d1.z ^ par) | (d2.x ^ par) | (d2.z ^ par) |
                       (d3.x ^ par) | (d3.z ^ par);
        need = !__all((bad & 1u) == 0u);
      }

      if (need) {
        // masked progressive probe: lanes whose granule already matched
        // stop re-loading -> chip-wide probe traffic decays as publishers
        // land instead of staying at full sweep rate.
        bool done = false;
        int guard = 0;
        while (true) {
          if (!done) {
            u64 pr;
            asm volatile(
                "global_load_dwordx2 %0, %1, off sc1\n\t"
                "s_waitcnt vmcnt(0)"
                : "=v"(pr) : "v"((const u64*)a0) : "memory");
            done = (((unsigned)pr ^ par) & 1u) == 0u;
          }
          if (__all(done)) break;
          if (++guard > vlimit) { vlimit = 256; break; }  // anti-hang valve
        }

        // full fetch + verify (sibling sectors may stagger; usually 1 pass)
        guard = 0;
        while (true) {
          asm volatile(
              "global_load_dwordx4 %0, %4, off sc1\n\t"
              "global_load_dwordx4 %1, %5, off sc1\n\t"
              "global_load_dwordx4 %2, %6, off sc1\n\t"
              "global_load_dwordx4 %3, %7, off sc1\n\t"
              "s_waitcnt vmcnt(0)"
              : "=v"(d0), "=v"(d1), "=v"(d2), "=v"(d3)
              : "v"(a0), "v"(a1), "v"(a2), "v"(a3)
              : "memory");
          unsigned bad = (d0.x ^ par) | (d0.z ^ par) | (d1.x ^ par) |
                         (d1.z ^ par) | (d2.x ^ par) | (d2.z ^ par) |
                         (d3.x ^ par) | (d3.z ^ par);
          if (__all((bad & 1u) == 0u)) break;
          if (++guard > vlimit) { vlimit = 256; break; }  // anti-hang valve
        }
      }

      // stage to wave-private LDS region (DS ops in-order within a wave;
      // this wave's MFMA reads exactly the region it writes -> no barrier)
      *(v4u*)(rbuf64 + 0 * 1032 + tid * 2) = d0;
      *(v4u*)(rbuf64 + 1 * 1032 + tid * 2) = d1;
      *(v4u*)(rbuf64 + 2 * 1032 + tid * 2) = d2;
      *(v4u*)(rbuf64 + 3 * 1032 + tid * 2) = d3;
    }

    // ---- noise prefetch for step t+1: issued AFTER discovery (so its HBM
    // latency is NOT inside this step's vmcnt(0) drains) and BEFORE the
    // MFMA/barrier (so it retires across barrier + tail, off the gating
    // path -- the raw barrier below does not drain vmcnt).
    float4 nz_next = {0.f, 0.f, 0.f, 0.f};
    if (wave == 0) {
      int tn = (t < NSTEP - 1) ? t + 1 : t;
      nz_next = *(const float4*)(noise + (size_t)tn * NC + row0 + g * 4);
    }

    // ---- B-frags: lane holds r[b=n&3][k = wave*512+f*32+g*8+j]
    // 4 independent accumulator chains: dependent-latency -> issue-limited
    const unsigned short* rb = rbufs + (n & 3) * 4128 + wave * 512 + g * 8;
    v4f ac0 = {0.f, 0.f, 0.f, 0.f}, ac1 = {0.f, 0.f, 0.f, 0.f};
    v4f ac2 = {0.f, 0.f, 0.f, 0.f}, ac3 = {0.f, 0.f, 0.f, 0.f};
#pragma unroll
    for (int f = 0; f < 16; f += 4) {
      v8s b0 = *(const v8s*)(rb + (f + 0) * 32);
      v8s b1 = *(const v8s*)(rb + (f + 1) * 32);
      v8s b2 = *(const v8s*)(rb + (f + 2) * 32);
      v8s b3 = *(const v8s*)(rb + (f + 3) * 32);
      ac0 = __builtin_amdgcn_mfma_f32_16x16x32_bf16(wfrag[f + 0], b0, ac0, 0, 0, 0);
      ac1 = __builtin_amdgcn_mfma_f32_16x16x32_bf16(wfrag[f + 1], b1, ac1, 0, 0, 0);
      ac2 = __builtin_amdgcn_mfma_f32_16x16x32_bf16(wfrag[f + 2], b2, ac2, 0, 0, 0);
      ac3 = __builtin_amdgcn_mfma_f32_16x16x32_bf16(wfrag[f + 3], b3, ac3, 0, 0, 0);
    }
    red[slot][wave][lane] = (ac0 + ac1) + (ac2 + ac3);
    barrier_lds_only();  // reduction barrier; vmem stays in flight

    if (wave == 0) {
      // pairwise tree: 3-deep dependent chain instead of 7-deep
      v4f s01 = red[slot][0][lane] + red[slot][1][lane];
      v4f s23 = red[slot][2][lane] + red[slot][3][lane];
      v4f s45 = red[slot][4][lane] + red[slot][5][lane];
      v4f s67 = red[slot][6][lane] + red[slot][7][lane];
      v4f s = (s01 + s23) + (s45 + s67);
      const int ph = t / 500;  // 0 fix, 1 sample, 2 delay, 3 test, 4 response
#pragma unroll
      for (int q = 0; q < 4; ++q) {
        float e = (ph == 1) ? esmp[q] : ((ph == 3) ? etst[q] : 0.f);
        float pre = s[q] + bias[q] + e;
        float rl = pre > 0.f ? pre : 0.f;
        float nq = (q == 0) ? nz_cur.x : (q == 1) ? nz_cur.y
                 : (q == 2) ? nz_cur.z : nz_cur.w;
        rst[q] = 0.8f * rst[q] + 0.2f * rl + 0.02f * nq;
      }
      if (n < 4) {  // publish FIRST (before bookkeeping): every cycle earlier
                    // here is a cycle off every consumer's discovery chain.
        u64 v = (u64)pack_bf2(rst[0], rst[1]) |
                ((u64)pack_bf2(rst[2], rst[3]) << 32);
        v = (v & ~1ull) | (u64)(((t + 1) >> 1) & 1u);
        u64* dst =
            (u64*)(ring + ((size_t)((t + 1) & 1) * 4 + n) * NC + row0 + g * 4);
        asm volatile("global_atomic_swap_x2 %0, %1, off sc1"
                     :: "v"(dst), "v"(v) : "memory");
      }
      if (t >= 1000 && t < 1500) {
#pragma unroll
        for (int q = 0; q < 4; ++q) tmem[q] += rst[q];
      }
      if (t >= 2000) {
#pragma unroll
        for (int q = 0; q < 4; ++q) tout[q] += rst[q];
      }
      nz_cur = nz_next;  // pipelined noise: consumed next step
      // no ack, no tag: validity travels inside the data
    }
  }

  // ---- readout partials: out[s][b][o] += sum_i w[o][i] * tsum[b][i]
  if (wave == 0) {
    float pm0 = 0, pm1 = 0, po0 = 0, po1 = 0;
#pragma unroll
    for (int q = 0; q < 4; ++q) {
      int i = row0 + g * 4 + q;
      pm0 += mem_w[i] * tmem[q];
      pm1 += mem_w[NC + i] * tmem[q];
      po0 += out_w[i] * tout[q];
      po1 += out_w[NC + i] * tout[q];
    }
    pm0 += __shfl_xor(pm0, 16); pm0 += __shfl_xor(pm0, 32);
    pm1 += __shfl_xor(pm1, 16); pm1 += __shfl_xor(pm1, 32);
    po0 += __shfl_xor(po0, 16); po0 += __shfl_xor(po0, 32);
    po1 += __shfl_xor(po1, 16); po1 += __shfl_xor(po1, 32);
    if (lane < 4) {
      atomicAdd(&accum[lane * 2 + 0], pm0);
      atomicAdd(&accum[lane * 2 + 1], pm1);
      atomicAdd(&accum[8 + lane * 2 + 0], po0);
      atomicAdd(&accum[8 + lane * 2 + 1], po1);
    }
  }
}

// Output is FLOAT32 (reference returns f32)
__global__ void rnn_final(const float* __restrict__ ws, float* __restrict__ out) {
  int i = threadIdx.x;
  if (i < 16) out[i] = ws[256 + i] * (1.0f / 500.0f);
}

extern "C" void kernel_launch(void* const* d_in, const int* in_sizes, int n_in,
                              void* d_out, int out_size, void* d_ws, size_t ws_size,
                              hipStream_t stream) {
  (void)in_sizes; (void)n_in; (void)out_size; (void)ws_size;
  const float* x     = (const float*)d_in[0];
  const float* rec_w = (const float*)d_in[1];
  const float* rec_b = (const float*)d_in[2];
  const float* inp_w = (const float*)d_in[3];
  const float* out_w = (const float*)d_in[4];
  const float* mem_w = (const float*)d_in[5];
  const float* noise = (const float*)d_in[6];
  float* ws = (float*)d_ws;

  rnn_init<<<(WS_WORDS + 255) / 256, 256, 0, stream>>>((unsigned*)d_ws);
  rnn_persist<<<256, 512, 0, stream>>>(x, rec_w, rec_b, inp_w, out_w, mem_w,
                                       noise, ws);
  rnn_final<<<1, 64, 0, stream>>>(ws, (float*)d_out);
}